// Round 16
// baseline (88.289 us; speedup 1.0000x reference)
//
#include <hip/hip_runtime.h>
#include <hip/hip_bf16.h>
#include <math.h>

#define B_DIM 4
#define C_DIM 256
#define CQK_DIM 32
#define N_POS 4096
#define NPART 4          // j-split partitions (16 tiles each)
#define LOG2E 1.4426950408889634f

typedef unsigned short u16;
typedef __attribute__((ext_vector_type(8))) short bf16x8;
typedef __attribute__((ext_vector_type(4))) float f32x4;

__device__ __forceinline__ u16 f32_to_bf16_rn(float f) {
    union { float f; unsigned int u; } v; v.f = f;
    unsigned int u = v.u;
    u += 0x7fffu + ((u >> 16) & 1u);
    return (u16)(u >> 16);
}
__device__ __forceinline__ float bf16_to_f32(u16 h) {
    union { unsigned int u; float f; } v; v.u = ((unsigned int)h) << 16;
    return v.f;
}
// packed bf16 convert (gfx950): dst = {lo16: bf16(a), hi16: bf16(b)}, RNE —
// bit-identical to f32_to_bf16_rn. Used ONLY in flash's P-pack (R23: inline
// asm conversion in proj's load path serializes the scheduler, +7 us).
__device__ __forceinline__ unsigned pk_bf16(float a, float b) {
    unsigned r;
    asm("v_cvt_pk_bf16_f32 %0, %1, %2" : "=v"(r) : "v"(a), "v"(b));
    return r;
}
__device__ __forceinline__ void async_copy16(const u16* g, u16* l) {
    __builtin_amdgcn_global_load_lds(
        (const __attribute__((address_space(1))) void*)g,
        (__attribute__((address_space(3))) void*)l, 16, 0, 0);
}

// ---------------------------------------------------------------------------
// FRAGMENT-ORDER LAYOUTS (R10): operand fragment = 64 lanes x 8 bf16.
//  V B-frag (cb,kb): lane l,e -> V[c=cb*16+(l&15)]
//                               [j=(2*kb+(e>>2))*16 + 4*(l>>4) + (e&3)]
//    frag_id=cb*2+kb. This k<->j permutation matches the NATIVE layout of
//    S^T = mfma(K,Q) accumulators -> P A-frags formed in-register, 0 shuffles.
//  K B/A-frag (jb): lane l,e -> K[j=jb*16+(l&15)][cqk=(l>>4)*8+e], frag_id=jb
//  Q B-frag (m):    lane l,e -> Q[i=m*16+(l&15)][cqk=(l>>4)*8+e]
// ---------------------------------------------------------------------------

// ---------------------------------------------------------------------------
// Projection (R25 = R17 + FULL UNROLL of the kk loop). proj is load-latency
// bound at 1 wave/SIMD (R19: extra TLP neutral; R18: dedup hurt; R23: fewer
// VALU ops hurt). The rolled kk loop gave the scheduler no window to hoist
// iteration kk+1's 32 independent strided x-loads under kk's convert+MFMA
// stream. Full unroll = pure ILP; register budget is free (1 block/CU ->
// up to ~512 VGPR/wave with zero occupancy cost). Arithmetic order identical.
// ---------------------------------------------------------------------------
__global__ __launch_bounds__(256) void proj_kernel(
    const float* __restrict__ x,
    const float* __restrict__ Wq, const float* __restrict__ bq,
    const float* __restrict__ Wk, const float* __restrict__ bk,
    const float* __restrict__ Wv, const float* __restrict__ bv,
    u16* __restrict__ qhi, u16* __restrict__ qlo,
    u16* __restrict__ kth, u16* __restrict__ ktl,
    u16* __restrict__ vtile)
{
    const int t    = threadIdx.x;
    const int blk  = blockIdx.x;        // 0..255 = (b, jt)
    const int b    = blk >> 6;
    const int jt   = blk & 63;
    const int n0   = jt * 64;
    const int wave = t >> 6;
    const int lane = t & 63;
    const int n16  = lane & 15;
    const int quad = lane >> 4;
    const float* xb = x + (size_t)b * C_DIM * N_POS;

    f32x4 accV[4][4];
    f32x4 accQ[4];
    #pragma unroll
    for (int v = 0; v < 4; ++v)
        #pragma unroll
        for (int nt = 0; nt < 4; ++nt) accV[v][nt] = (f32x4){0.f,0.f,0.f,0.f};
    #pragma unroll
    for (int nt = 0; nt < 4; ++nt) accQ[nt] = (f32x4){0.f,0.f,0.f,0.f};

    const float* Wqk  = (wave < 2) ? Wq : Wk;
    const int    qkrow = (wave & 1) * 16 + n16;

    #pragma unroll
    for (int kk = 0; kk < 8; ++kk) {
        const int k0 = kk * 32 + quad * 8;
        bf16x8 bh[4], bl[4];
        #pragma unroll
        for (int nt = 0; nt < 4; ++nt) {
            const float* xp = xb + (size_t)k0 * N_POS + n0 + nt * 16 + n16;
            float xv[8];
            #pragma unroll
            for (int j = 0; j < 8; ++j) xv[j] = xp[(size_t)j * N_POS];
            #pragma unroll
            for (int j = 0; j < 8; ++j) {
                u16 h = f32_to_bf16_rn(xv[j]);
                bh[nt][j] = (short)h;
                bl[nt][j] = (short)f32_to_bf16_rn(xv[j] - bf16_to_f32(h));
            }
        }
        #pragma unroll
        for (int v = 0; v < 4; ++v) {
            const float* wr = Wv + (size_t)(wave * 64 + v * 16 + n16) * C_DIM + k0;
            float4 a0 = *(const float4*)(wr);
            float4 a1 = *(const float4*)(wr + 4);
            bf16x8 ah;
            ah[0] = (short)f32_to_bf16_rn(a0.x); ah[1] = (short)f32_to_bf16_rn(a0.y);
            ah[2] = (short)f32_to_bf16_rn(a0.z); ah[3] = (short)f32_to_bf16_rn(a0.w);
            ah[4] = (short)f32_to_bf16_rn(a1.x); ah[5] = (short)f32_to_bf16_rn(a1.y);
            ah[6] = (short)f32_to_bf16_rn(a1.z); ah[7] = (short)f32_to_bf16_rn(a1.w);
            #pragma unroll
            for (int nt = 0; nt < 4; ++nt)
                accV[v][nt] = __builtin_amdgcn_mfma_f32_16x16x32_bf16(
                    ah, bh[nt], accV[v][nt], 0, 0, 0);
        }
        {
            const float* wr = Wqk + (size_t)qkrow * C_DIM + k0;
            bf16x8 ah, al;
            #pragma unroll
            for (int j = 0; j < 8; ++j) {
                float w = wr[j];
                u16 h = f32_to_bf16_rn(w);
                ah[j] = (short)h;
                al[j] = (short)f32_to_bf16_rn(w - bf16_to_f32(h));
            }
            #pragma unroll
            for (int nt = 0; nt < 4; ++nt) {
                accQ[nt] = __builtin_amdgcn_mfma_f32_16x16x32_bf16(ah, bh[nt], accQ[nt], 0, 0, 0);
                accQ[nt] = __builtin_amdgcn_mfma_f32_16x16x32_bf16(ah, bl[nt], accQ[nt], 0, 0, 0);
                accQ[nt] = __builtin_amdgcn_mfma_f32_16x16x32_bf16(al, bh[nt], accQ[nt], 0, 0, 0);
            }
        }
    }

    // ---- V stores, fragment order with S^T-native k-permutation:
    //  value (c = cb*16+quad*4+r, j-within-tile = nt*16+n16) lands at
    //  frag (cb, kb=nt>>1), lane l' = (n16>>2)*16 + quad*4 + r,
    //  element e = (nt&1)*4 + (n16&3).
    u16* vt = vtile + (size_t)(b * 64 + jt) * (32 * 512);
    #pragma unroll
    for (int v = 0; v < 4; ++v) {
        const int cb = wave * 4 + v;
        #pragma unroll
        for (int r = 0; r < 4; ++r) {
            const int c = cb * 16 + quad * 4 + r;
            const float bias = bv[c];
            #pragma unroll
            for (int nt = 0; nt < 4; ++nt) {
                const int kb = nt >> 1;
                vt[(cb * 2 + kb) * 512
                   + ((n16 >> 2) * 16 + quad * 4 + r) * 8
                   + (nt & 1) * 4 + (n16 & 3)] =
                    f32_to_bf16_rn(accV[v][nt][r] + bias);
            }
        }
    }
    if (wave < 2) {
        #pragma unroll
        for (int r = 0; r < 4; ++r) {
            const int c = (wave & 1) * 16 + quad * 4 + r;
            const float bias = bq[c];
            #pragma unroll
            for (int nt = 0; nt < 4; ++nt) {
                float val = (accQ[nt][r] + bias) * LOG2E;   // exp2 folding
                u16 h = f32_to_bf16_rn(val);
                u16 lo = f32_to_bf16_rn(val - bf16_to_f32(h));
                size_t base = ((size_t)b * N_POS + n0 + nt * 16 + n16) * CQK_DIM + c;
                qhi[base] = h; qlo[base] = lo;
            }
        }
    } else {
        u16* kh_t = kth + (size_t)(b * 64 + jt) * (4 * 512);
        u16* kl_t = ktl + (size_t)(b * 64 + jt) * (4 * 512);
        #pragma unroll
        for (int r = 0; r < 4; ++r) {
            const int c = (wave & 1) * 16 + quad * 4 + r;
            const float bias = bk[c];
            #pragma unroll
            for (int nt = 0; nt < 4; ++nt) {
                float val = accQ[nt][r] + bias;
                u16 h = f32_to_bf16_rn(val);
                u16 lo = f32_to_bf16_rn(val - bf16_to_f32(h));
                const int off = nt * 512 + ((c >> 3) * 16 + n16) * 8 + (c & 7);
                kh_t[off] = h; kl_t[off] = lo;
            }
        }
    }
}

// ---------------------------------------------------------------------------
// Flash attention (R22-exact — proven 52.8 us): 512-thread blocks, 8 waves
// own 256 i-rows (m=2 each), grid 256 = 1 block/CU; per-block overheads
// (40 KB tile DMA, K ds_reads, barriers) amortize over 2x i-rows. KVBLK=64,
// 2-buffer 80 KB LDS, one barrier/tile, K frags read BEFORE STAGE issue
// (R21), DMA a full tile old at its drain (R13), swapped QK^T in-register P
// (R10), bare v_exp_f32 with log2e pre-folded into q (R17).
// ---------------------------------------------------------------------------
__global__ __launch_bounds__(512, 2) void flash_kernel(
    const u16* __restrict__ qhi, const u16* __restrict__ qlo,
    const u16* __restrict__ kth, const u16* __restrict__ ktl,
    const u16* __restrict__ vtile,
    u16* __restrict__ part, float2* __restrict__ ml)
{
    __shared__ u16 Vt[2][40 * 512];   // 80 KB: ch 0..31 = V frags, 32..35 = Khi, 36..39 = Klo

    const int t    = threadIdx.x;
    const int wave = t >> 6;            // 0..7
    const int lane = t & 63;
    const int n16  = lane & 15;
    const int quad = lane >> 4;

    const int idx    = blockIdx.x;          // 0..255
    const int xcd    = idx & 7;
    const int b      = xcd & 3;             // pins batch b's V/K to this XCD's L2
    const int z      = idx >> 3;            // 0..31
    const int p      = z & 3;
    const int iouter = z >> 2;              // 0..7
    const int itile  = (iouter << 1) | (xcd >> 2);   // 0..15
    const int i0     = itile * 256 + wave * 32;      // wave's 32 rows

    bf16x8 qh[2], ql[2];
    #pragma unroll
    for (int m = 0; m < 2; ++m) {
        qh[m] = *(const bf16x8*)(qhi + ((size_t)b * N_POS + i0 + m * 16 + n16) * CQK_DIM + quad * 8);
        ql[m] = *(const bf16x8*)(qlo + ((size_t)b * N_POS + i0 + m * 16 + n16) * CQK_DIM + quad * 8);
    }

    f32x4 O[2][16];   // O[m][cb]: rows i0+m*16+quad*4+r, cols cb*16+n16
    #pragma unroll
    for (int m = 0; m < 2; ++m)
        #pragma unroll
        for (int cb = 0; cb < 16; ++cb) O[m][cb] = (f32x4){0.f, 0.f, 0.f, 0.f};
    float lsum[2] = {0.f, 0.f};   // lane-local: row i = m*16 + n16

    const int jt_beg = p * 16;
    const int jt_end = jt_beg + 16;

    const u16* vb_base = vtile + (size_t)b * 64 * (32 * 512);
    const u16* kh_base = kth   + (size_t)b * 64 * (4 * 512);
    const u16* kl_base = ktl   + (size_t)b * 64 * (4 * 512);

    // stage tile JT (V + Khi + Klo) into buffer BUF: 40 channels, 5 per wave
#define STAGE(JT, BUF)                                                          \
    {                                                                           \
        const u16* vsrc  = vb_base + (size_t)(JT) * (32 * 512);                 \
        const u16* khsrc = kh_base + (size_t)(JT) * (4 * 512);                  \
        const u16* klsrc = kl_base + (size_t)(JT) * (4 * 512);                  \
        for (int ch = wave; ch < 32; ch += 8)                                   \
            async_copy16(vsrc + ch * 512 + lane * 8, Vt[BUF] + ch * 512);       \
        for (int ch = wave; ch < 8; ch += 8)                                    \
            async_copy16((ch < 4 ? khsrc + ch * 512 : klsrc + (ch - 4) * 512)   \
                             + lane * 8,                                        \
                         Vt[BUF] + (32 + ch) * 512);                            \
    }

    // ---- prologue: stage first tile into buf 0
    STAGE(jt_beg, 0);

    int buf = 0;
    for (int jt = jt_beg; jt < jt_end; ++jt) {
        __syncthreads();   // drains DMA issued one full tile ago -> ~free

        // ---- K frags from LDS FIRST (R21 reorder): their ~120cy latency
        // drains under the STAGE issue stream below instead of gating QK.
        const u16* kbuf = Vt[buf];
        bf16x8 kh[4], kl[4];
        #pragma unroll
        for (int jb = 0; jb < 4; ++jb) {
            kh[jb] = *(const bf16x8*)(kbuf + (32 + jb) * 512 + lane * 8);
            kl[jb] = *(const bf16x8*)(kbuf + (36 + jb) * 512 + lane * 8);
        }

        // ---- issue DMA for jt+1 (writes buf^1; drained at the next barrier)
        if (jt + 1 < jt_end) STAGE(jt + 1, buf ^ 1);

        // ---- S^T = K q^T (3-pass hi/lo): lane holds S[i=m*16+n16][j=jb*16+quad*4+r]
        f32x4 s[2][4];
        __builtin_amdgcn_s_setprio(1);
        #pragma unroll
        for (int m = 0; m < 2; ++m)
            #pragma unroll
            for (int jb = 0; jb < 4; ++jb) {
                f32x4 acc = (f32x4){0.f, 0.f, 0.f, 0.f};
                acc = __builtin_amdgcn_mfma_f32_16x16x32_bf16(kh[jb], qh[m], acc, 0, 0, 0);
                acc = __builtin_amdgcn_mfma_f32_16x16x32_bf16(kl[jb], qh[m], acc, 0, 0, 0);
                acc = __builtin_amdgcn_mfma_f32_16x16x32_bf16(kh[jb], ql[m], acc, 0, 0, 0);
                s[m][jb] = acc;
            }
        __builtin_amdgcn_s_setprio(0);

        // ---- no-max softmax: bare v_exp_f32 (q pre-scaled by log2e) +
        // in-register P A-frag packing via cvt_pk
        bf16x8 Pf[2][2];
        #pragma unroll
        for (int m = 0; m < 2; ++m)
            #pragma unroll
            for (int kb = 0; kb < 2; ++kb) {
                union { bf16x8 v; unsigned u[4]; } tmp;
                #pragma unroll
                for (int j2 = 0; j2 < 2; ++j2) {
                    const int jb = kb * 2 + j2;
                    float p0 = __builtin_amdgcn_exp2f(s[m][jb][0]);
                    float p1 = __builtin_amdgcn_exp2f(s[m][jb][1]);
                    float p2 = __builtin_amdgcn_exp2f(s[m][jb][2]);
                    float p3 = __builtin_amdgcn_exp2f(s[m][jb][3]);
                    lsum[m] += (p0 + p1) + (p2 + p3);
                    tmp.u[j2 * 2 + 0] = pk_bf16(p0, p1);
                    tmp.u[j2 * 2 + 1] = pk_bf16(p2, p3);
                }
                Pf[m][kb] = tmp.v;
            }

        // ---- PV: P A-frags in-register, V B-frags from LDS (conflict-free)
        const u16* vb = Vt[buf];
        __builtin_amdgcn_s_setprio(1);
        #pragma unroll
        for (int kb = 0; kb < 2; ++kb) {
            #pragma unroll
            for (int cb = 0; cb < 16; ++cb) {
                bf16x8 Vf = *(const bf16x8*)(vb + (cb * 2 + kb) * 512 + lane * 8);
                #pragma unroll
                for (int m = 0; m < 2; ++m)
                    O[m][cb] = __builtin_amdgcn_mfma_f32_16x16x32_bf16(
                        Pf[m][kb], Vf, O[m][cb], 0, 0, 0);
            }
        }
        __builtin_amdgcn_s_setprio(0);
        buf ^= 1;
    }
#undef STAGE

    // ---- l: full row sum = reduce lane-local partials across the 4 quads
    #pragma unroll
    for (int m = 0; m < 2; ++m) {
        lsum[m] += __shfl_xor(lsum[m], 16, 64);
        lsum[m] += __shfl_xor(lsum[m], 32, 64);
    }
    // O rows are i = m*16 + quad*4 + r; fetch that row's sum (held at lane n16 = quad*4+r)
    float inv_l[2][4];
    #pragma unroll
    for (int m = 0; m < 2; ++m)
        #pragma unroll
        for (int r = 0; r < 4; ++r)
            inv_l[m][r] = 1.f / __shfl(lsum[m], quad * 4 + r, 64);

    // ---- store normalized partials + (m=0, l)
    u16* pbase = part + ((size_t)(p * 4 + b) * N_POS + i0) * C_DIM;
    #pragma unroll
    for (int m = 0; m < 2; ++m)
        #pragma unroll
        for (int cb = 0; cb < 16; ++cb)
            #pragma unroll
            for (int r = 0; r < 4; ++r)
                pbase[(size_t)(m * 16 + quad * 4 + r) * C_DIM + cb * 16 + n16] =
                    f32_to_bf16_rn(O[m][cb][r] * inv_l[m][r]);
    if (quad == 0) {
        #pragma unroll
        for (int m = 0; m < 2; ++m)
            ml[(size_t)(p * 4 + b) * N_POS + i0 + m * 16 + n16] =
                make_float2(0.f, lsum[m]);
    }
}

// ---------------------------------------------------------------------------
// Reduce (R16 vectorized, kept): bf16x8 part loads (16 B/lane — G13),
// transpose via LDS, + residual. ~95% of its 10.4 us BW floor.
// ---------------------------------------------------------------------------
__global__ __launch_bounds__(256) void reduce_kernel(
    const u16* __restrict__ part, const float2* __restrict__ ml,
    const float* __restrict__ x, float* __restrict__ out)
{
    const int TJ = 32;
    __shared__ float wgt[NPART][TJ];
    __shared__ float trans[C_DIM][TJ + 1];

    const int t   = threadIdx.x;
    const int blk = blockIdx.x;      // 0..511
    const int b   = blk >> 7;
    const int n0  = (blk & 127) * TJ;

    if (t < TJ) {
        int i = n0 + t;
        float s = 0.f, w[NPART];
        #pragma unroll
        for (int p = 0; p < NPART; ++p) {
            float2 a = ml[(size_t)(p * 4 + b) * N_POS + i];
            w[p] = a.y;          // m == 0 for all partitions
            s += w[p];
        }
        float inv = 1.f / s;
        #pragma unroll
        for (int p = 0; p < NPART; ++p) wgt[p][t] = w[p] * inv;
    }
    __syncthreads();

    {
        const int cp = t & 31;     // 8 channels: cp*8 .. cp*8+7
        const int ih = t >> 5;     // 8 rows in flight
        for (int ib = 0; ib < TJ; ib += 8) {
            const int i = ib + ih;
            float acc[8] = {0.f, 0.f, 0.f, 0.f, 0.f, 0.f, 0.f, 0.f};
            #pragma unroll
            for (int p = 0; p < NPART; ++p) {
                const u16* row = part + ((size_t)(p * 4 + b) * N_POS + n0 + i) * C_DIM;
                bf16x8 pv = *(const bf16x8*)(row + cp * 8);
                const float wp = wgt[p][i];
                #pragma unroll
                for (int e = 0; e < 8; ++e)
                    acc[e] += wp * bf16_to_f32((u16)pv[e]);
            }
            #pragma unroll
            for (int e = 0; e < 8; ++e)
                trans[cp * 8 + e][i] = acc[e];
        }
    }
    __syncthreads();

    {
        const int il = t & 31;
        const int cr = t >> 5;
        const float* xb = x + (size_t)b * C_DIM * N_POS;
        float* ob       = out + (size_t)b * C_DIM * N_POS;
        for (int cc = 0; cc < 32; ++cc) {
            int c = cc * 8 + cr;
            size_t g = (size_t)c * N_POS + n0 + il;
            ob[g] = trans[c][il] + xb[g];
        }
    }
}

extern "C" void kernel_launch(void* const* d_in, const int* in_sizes, int n_in,
                              void* d_out, int out_size, void* d_ws, size_t ws_size,
                              hipStream_t stream) {
    const float* x  = (const float*)d_in[0];
    const float* Wq = (const float*)d_in[1];
    const float* bq = (const float*)d_in[2];
    const float* Wk = (const float*)d_in[3];
    const float* bk = (const float*)d_in[4];
    const float* Wv = (const float*)d_in[5];
    const float* bv = (const float*)d_in[6];
    float* out = (float*)d_out;

    // ws layout (44.5 MiB == R1-proven bound):
    //   0 MiB  qhi (1)   1 MiB  qlo (1)
    //   2 MiB  kth [B,64,4,512] u16 (1)   3 MiB  ktl (1)
    //   4 MiB  vtile [B,64,32,512] u16 (8)
    //  12 MiB  part [4,B,N,C] bf16 (32)
    //  44 MiB  ml [4,B,N] float2 (0.5)
    char* ws = (char*)d_ws;
    u16*    qhi   = (u16*)(ws);
    u16*    qlo   = (u16*)(ws + (1ull << 20));
    u16*    kth   = (u16*)(ws + (2ull << 20));
    u16*    ktl   = (u16*)(ws + (3ull << 20));
    u16*    vtile = (u16*)(ws + (4ull << 20));
    u16*    part  = (u16*)(ws + (12ull << 20));
    float2* mlp   = (float2*)(ws + (44ull << 20));

    hipLaunchKernelGGL(proj_kernel, dim3(256), dim3(256), 0, stream,
                       x, Wq, bq, Wk, bk, Wv, bv, qhi, qlo, kth, ktl, vtile);
    hipLaunchKernelGGL(flash_kernel, dim3(256), dim3(512), 0, stream,
                       qhi, qlo, kth, ktl, vtile, part, mlp);
    hipLaunchKernelGGL(reduce_kernel, dim3(512), dim3(256), 0, stream,
                       part, mlp, x, out);
}

// Round 17
// 84.462 us; speedup vs baseline: 1.0453x; 1.0453x over previous
//
#include <hip/hip_runtime.h>
#include <hip/hip_bf16.h>
#include <math.h>

#define B_DIM 4
#define C_DIM 256
#define CQK_DIM 32
#define N_POS 4096
#define NPART 4          // j-split partitions (16 tiles each)
#define LOG2E 1.4426950408889634f

typedef unsigned short u16;
typedef __attribute__((ext_vector_type(8))) short bf16x8;
typedef __attribute__((ext_vector_type(4))) float f32x4;

__device__ __forceinline__ u16 f32_to_bf16_rn(float f) {
    union { float f; unsigned int u; } v; v.f = f;
    unsigned int u = v.u;
    u += 0x7fffu + ((u >> 16) & 1u);
    return (u16)(u >> 16);
}
__device__ __forceinline__ float bf16_to_f32(u16 h) {
    union { unsigned int u; float f; } v; v.u = ((unsigned int)h) << 16;
    return v.f;
}
// packed bf16 convert (gfx950): dst = {lo16: bf16(a), hi16: bf16(b)}, RNE —
// bit-identical to f32_to_bf16_rn. Used ONLY in flash's P-pack (R23: inline
// asm conversion in proj's load path serializes the scheduler, +7 us).
__device__ __forceinline__ unsigned pk_bf16(float a, float b) {
    unsigned r;
    asm("v_cvt_pk_bf16_f32 %0, %1, %2" : "=v"(r) : "v"(a), "v"(b));
    return r;
}
__device__ __forceinline__ void async_copy16(const u16* g, u16* l) {
    __builtin_amdgcn_global_load_lds(
        (const __attribute__((address_space(1))) void*)g,
        (__attribute__((address_space(3))) void*)l, 16, 0, 0);
}

// ---------------------------------------------------------------------------
// FRAGMENT-ORDER LAYOUTS (R10): operand fragment = 64 lanes x 8 bf16.
//  V B-frag (cb,kb): lane l,e -> V[c=cb*16+(l&15)]
//                               [j=(2*kb+(e>>2))*16 + 4*(l>>4) + (e&3)]
//    frag_id=cb*2+kb. This k<->j permutation matches the NATIVE layout of
//    S^T = mfma(K,Q) accumulators -> P A-frags formed in-register, 0 shuffles.
//  K B/A-frag (jb): lane l,e -> K[j=jb*16+(l&15)][cqk=(l>>4)*8+e], frag_id=jb
//  Q B-frag (m):    lane l,e -> Q[i=m*16+(l&15)][cqk=(l>>4)*8+e]
// ---------------------------------------------------------------------------

// ---------------------------------------------------------------------------
// Projection (R17-exact, champion): R7/R8 MFMA GEMM, zero LDS; fragment-
// order V/K stores; LOG2E folded into q so flash uses bare v_exp_f32.
// Proj attack ledger (ALL worse): wconv-hoist (R16 +4), LDS x-dedup (R18
// +6), 8-wave TLP (R19 0), pk_bf16 convert (R23 +7), full kk-unroll (R25
// +4). The ROLLED loop with manual convert is the optimum: conversion
// arithmetic doubles as load-latency cover at exactly the right register
// pressure for the scheduler's loop-carried overlap.
// ---------------------------------------------------------------------------
__global__ __launch_bounds__(256) void proj_kernel(
    const float* __restrict__ x,
    const float* __restrict__ Wq, const float* __restrict__ bq,
    const float* __restrict__ Wk, const float* __restrict__ bk,
    const float* __restrict__ Wv, const float* __restrict__ bv,
    u16* __restrict__ qhi, u16* __restrict__ qlo,
    u16* __restrict__ kth, u16* __restrict__ ktl,
    u16* __restrict__ vtile)
{
    const int t    = threadIdx.x;
    const int blk  = blockIdx.x;        // 0..255 = (b, jt)
    const int b    = blk >> 6;
    const int jt   = blk & 63;
    const int n0   = jt * 64;
    const int wave = t >> 6;
    const int lane = t & 63;
    const int n16  = lane & 15;
    const int quad = lane >> 4;
    const float* xb = x + (size_t)b * C_DIM * N_POS;

    f32x4 accV[4][4];
    f32x4 accQ[4];
    #pragma unroll
    for (int v = 0; v < 4; ++v)
        #pragma unroll
        for (int nt = 0; nt < 4; ++nt) accV[v][nt] = (f32x4){0.f,0.f,0.f,0.f};
    #pragma unroll
    for (int nt = 0; nt < 4; ++nt) accQ[nt] = (f32x4){0.f,0.f,0.f,0.f};

    const float* Wqk  = (wave < 2) ? Wq : Wk;
    const int    qkrow = (wave & 1) * 16 + n16;

    for (int kk = 0; kk < 8; ++kk) {
        const int k0 = kk * 32 + quad * 8;
        bf16x8 bh[4], bl[4];
        #pragma unroll
        for (int nt = 0; nt < 4; ++nt) {
            const float* xp = xb + (size_t)k0 * N_POS + n0 + nt * 16 + n16;
            float xv[8];
            #pragma unroll
            for (int j = 0; j < 8; ++j) xv[j] = xp[(size_t)j * N_POS];
            #pragma unroll
            for (int j = 0; j < 8; ++j) {
                u16 h = f32_to_bf16_rn(xv[j]);
                bh[nt][j] = (short)h;
                bl[nt][j] = (short)f32_to_bf16_rn(xv[j] - bf16_to_f32(h));
            }
        }
        #pragma unroll
        for (int v = 0; v < 4; ++v) {
            const float* wr = Wv + (size_t)(wave * 64 + v * 16 + n16) * C_DIM + k0;
            float4 a0 = *(const float4*)(wr);
            float4 a1 = *(const float4*)(wr + 4);
            bf16x8 ah;
            ah[0] = (short)f32_to_bf16_rn(a0.x); ah[1] = (short)f32_to_bf16_rn(a0.y);
            ah[2] = (short)f32_to_bf16_rn(a0.z); ah[3] = (short)f32_to_bf16_rn(a0.w);
            ah[4] = (short)f32_to_bf16_rn(a1.x); ah[5] = (short)f32_to_bf16_rn(a1.y);
            ah[6] = (short)f32_to_bf16_rn(a1.z); ah[7] = (short)f32_to_bf16_rn(a1.w);
            #pragma unroll
            for (int nt = 0; nt < 4; ++nt)
                accV[v][nt] = __builtin_amdgcn_mfma_f32_16x16x32_bf16(
                    ah, bh[nt], accV[v][nt], 0, 0, 0);
        }
        {
            const float* wr = Wqk + (size_t)qkrow * C_DIM + k0;
            bf16x8 ah, al;
            #pragma unroll
            for (int j = 0; j < 8; ++j) {
                float w = wr[j];
                u16 h = f32_to_bf16_rn(w);
                ah[j] = (short)h;
                al[j] = (short)f32_to_bf16_rn(w - bf16_to_f32(h));
            }
            #pragma unroll
            for (int nt = 0; nt < 4; ++nt) {
                accQ[nt] = __builtin_amdgcn_mfma_f32_16x16x32_bf16(ah, bh[nt], accQ[nt], 0, 0, 0);
                accQ[nt] = __builtin_amdgcn_mfma_f32_16x16x32_bf16(ah, bl[nt], accQ[nt], 0, 0, 0);
                accQ[nt] = __builtin_amdgcn_mfma_f32_16x16x32_bf16(al, bh[nt], accQ[nt], 0, 0, 0);
            }
        }
    }

    // ---- V stores, fragment order with S^T-native k-permutation:
    //  value (c = cb*16+quad*4+r, j-within-tile = nt*16+n16) lands at
    //  frag (cb, kb=nt>>1), lane l' = (n16>>2)*16 + quad*4 + r,
    //  element e = (nt&1)*4 + (n16&3).
    u16* vt = vtile + (size_t)(b * 64 + jt) * (32 * 512);
    #pragma unroll
    for (int v = 0; v < 4; ++v) {
        const int cb = wave * 4 + v;
        #pragma unroll
        for (int r = 0; r < 4; ++r) {
            const int c = cb * 16 + quad * 4 + r;
            const float bias = bv[c];
            #pragma unroll
            for (int nt = 0; nt < 4; ++nt) {
                const int kb = nt >> 1;
                vt[(cb * 2 + kb) * 512
                   + ((n16 >> 2) * 16 + quad * 4 + r) * 8
                   + (nt & 1) * 4 + (n16 & 3)] =
                    f32_to_bf16_rn(accV[v][nt][r] + bias);
            }
        }
    }
    if (wave < 2) {
        #pragma unroll
        for (int r = 0; r < 4; ++r) {
            const int c = (wave & 1) * 16 + quad * 4 + r;
            const float bias = bq[c];
            #pragma unroll
            for (int nt = 0; nt < 4; ++nt) {
                float val = (accQ[nt][r] + bias) * LOG2E;   // exp2 folding
                u16 h = f32_to_bf16_rn(val);
                u16 lo = f32_to_bf16_rn(val - bf16_to_f32(h));
                size_t base = ((size_t)b * N_POS + n0 + nt * 16 + n16) * CQK_DIM + c;
                qhi[base] = h; qlo[base] = lo;
            }
        }
    } else {
        u16* kh_t = kth + (size_t)(b * 64 + jt) * (4 * 512);
        u16* kl_t = ktl + (size_t)(b * 64 + jt) * (4 * 512);
        #pragma unroll
        for (int r = 0; r < 4; ++r) {
            const int c = (wave & 1) * 16 + quad * 4 + r;
            const float bias = bk[c];
            #pragma unroll
            for (int nt = 0; nt < 4; ++nt) {
                float val = accQ[nt][r] + bias;
                u16 h = f32_to_bf16_rn(val);
                u16 lo = f32_to_bf16_rn(val - bf16_to_f32(h));
                const int off = nt * 512 + ((c >> 3) * 16 + n16) * 8 + (c & 7);
                kh_t[off] = h; kl_t[off] = lo;
            }
        }
    }
}

// ---------------------------------------------------------------------------
// Flash attention (R22-exact — proven 52.8 us, twice): 512-thread blocks,
// 8 waves own 256 i-rows (m=2 each), grid 256 = 1 block/CU; per-block
// overheads (40 KB tile DMA, K ds_reads, barriers) amortize over 2x i-rows.
// KVBLK=64, 2-buffer 80 KB LDS, one barrier/tile, K frags read BEFORE STAGE
// issue (R21), DMA a full tile old at its drain (R13), swapped QK^T
// in-register P (R10), bare v_exp_f32 with log2e pre-folded into q (R17).
// Structural ledger (ALL worse): no-LDS direct (R12 102), reg K-prefetch
// (R11 spill 114), V-split to L1 (R14 60.5), m=1 2xTLP (R15 63), 3-slot
// ring KVBLK=32 (R20 58.2), libm exp2f (R16 63.3).
// ---------------------------------------------------------------------------
__global__ __launch_bounds__(512, 2) void flash_kernel(
    const u16* __restrict__ qhi, const u16* __restrict__ qlo,
    const u16* __restrict__ kth, const u16* __restrict__ ktl,
    const u16* __restrict__ vtile,
    u16* __restrict__ part, float2* __restrict__ ml)
{
    __shared__ u16 Vt[2][40 * 512];   // 80 KB: ch 0..31 = V frags, 32..35 = Khi, 36..39 = Klo

    const int t    = threadIdx.x;
    const int wave = t >> 6;            // 0..7
    const int lane = t & 63;
    const int n16  = lane & 15;
    const int quad = lane >> 4;

    const int idx    = blockIdx.x;          // 0..255
    const int xcd    = idx & 7;
    const int b      = xcd & 3;             // pins batch b's V/K to this XCD's L2
    const int z      = idx >> 3;            // 0..31
    const int p      = z & 3;
    const int iouter = z >> 2;              // 0..7
    const int itile  = (iouter << 1) | (xcd >> 2);   // 0..15
    const int i0     = itile * 256 + wave * 32;      // wave's 32 rows

    bf16x8 qh[2], ql[2];
    #pragma unroll
    for (int m = 0; m < 2; ++m) {
        qh[m] = *(const bf16x8*)(qhi + ((size_t)b * N_POS + i0 + m * 16 + n16) * CQK_DIM + quad * 8);
        ql[m] = *(const bf16x8*)(qlo + ((size_t)b * N_POS + i0 + m * 16 + n16) * CQK_DIM + quad * 8);
    }

    f32x4 O[2][16];   // O[m][cb]: rows i0+m*16+quad*4+r, cols cb*16+n16
    #pragma unroll
    for (int m = 0; m < 2; ++m)
        #pragma unroll
        for (int cb = 0; cb < 16; ++cb) O[m][cb] = (f32x4){0.f, 0.f, 0.f, 0.f};
    float lsum[2] = {0.f, 0.f};   // lane-local: row i = m*16 + n16

    const int jt_beg = p * 16;
    const int jt_end = jt_beg + 16;

    const u16* vb_base = vtile + (size_t)b * 64 * (32 * 512);
    const u16* kh_base = kth   + (size_t)b * 64 * (4 * 512);
    const u16* kl_base = ktl   + (size_t)b * 64 * (4 * 512);

    // stage tile JT (V + Khi + Klo) into buffer BUF: 40 channels, 5 per wave
#define STAGE(JT, BUF)                                                          \
    {                                                                           \
        const u16* vsrc  = vb_base + (size_t)(JT) * (32 * 512);                 \
        const u16* khsrc = kh_base + (size_t)(JT) * (4 * 512);                  \
        const u16* klsrc = kl_base + (size_t)(JT) * (4 * 512);                  \
        for (int ch = wave; ch < 32; ch += 8)                                   \
            async_copy16(vsrc + ch * 512 + lane * 8, Vt[BUF] + ch * 512);       \
        for (int ch = wave; ch < 8; ch += 8)                                    \
            async_copy16((ch < 4 ? khsrc + ch * 512 : klsrc + (ch - 4) * 512)   \
                             + lane * 8,                                        \
                         Vt[BUF] + (32 + ch) * 512);                            \
    }

    // ---- prologue: stage first tile into buf 0
    STAGE(jt_beg, 0);

    int buf = 0;
    for (int jt = jt_beg; jt < jt_end; ++jt) {
        __syncthreads();   // drains DMA issued one full tile ago -> ~free

        // ---- K frags from LDS FIRST (R21 reorder): their ~120cy latency
        // drains under the STAGE issue stream below instead of gating QK.
        const u16* kbuf = Vt[buf];
        bf16x8 kh[4], kl[4];
        #pragma unroll
        for (int jb = 0; jb < 4; ++jb) {
            kh[jb] = *(const bf16x8*)(kbuf + (32 + jb) * 512 + lane * 8);
            kl[jb] = *(const bf16x8*)(kbuf + (36 + jb) * 512 + lane * 8);
        }

        // ---- issue DMA for jt+1 (writes buf^1; drained at the next barrier)
        if (jt + 1 < jt_end) STAGE(jt + 1, buf ^ 1);

        // ---- S^T = K q^T (3-pass hi/lo): lane holds S[i=m*16+n16][j=jb*16+quad*4+r]
        f32x4 s[2][4];
        __builtin_amdgcn_s_setprio(1);
        #pragma unroll
        for (int m = 0; m < 2; ++m)
            #pragma unroll
            for (int jb = 0; jb < 4; ++jb) {
                f32x4 acc = (f32x4){0.f, 0.f, 0.f, 0.f};
                acc = __builtin_amdgcn_mfma_f32_16x16x32_bf16(kh[jb], qh[m], acc, 0, 0, 0);
                acc = __builtin_amdgcn_mfma_f32_16x16x32_bf16(kl[jb], qh[m], acc, 0, 0, 0);
                acc = __builtin_amdgcn_mfma_f32_16x16x32_bf16(kh[jb], ql[m], acc, 0, 0, 0);
                s[m][jb] = acc;
            }
        __builtin_amdgcn_s_setprio(0);

        // ---- no-max softmax: bare v_exp_f32 (q pre-scaled by log2e) +
        // in-register P A-frag packing via cvt_pk
        bf16x8 Pf[2][2];
        #pragma unroll
        for (int m = 0; m < 2; ++m)
            #pragma unroll
            for (int kb = 0; kb < 2; ++kb) {
                union { bf16x8 v; unsigned u[4]; } tmp;
                #pragma unroll
                for (int j2 = 0; j2 < 2; ++j2) {
                    const int jb = kb * 2 + j2;
                    float p0 = __builtin_amdgcn_exp2f(s[m][jb][0]);
                    float p1 = __builtin_amdgcn_exp2f(s[m][jb][1]);
                    float p2 = __builtin_amdgcn_exp2f(s[m][jb][2]);
                    float p3 = __builtin_amdgcn_exp2f(s[m][jb][3]);
                    lsum[m] += (p0 + p1) + (p2 + p3);
                    tmp.u[j2 * 2 + 0] = pk_bf16(p0, p1);
                    tmp.u[j2 * 2 + 1] = pk_bf16(p2, p3);
                }
                Pf[m][kb] = tmp.v;
            }

        // ---- PV: P A-frags in-register, V B-frags from LDS (conflict-free)
        const u16* vb = Vt[buf];
        __builtin_amdgcn_s_setprio(1);
        #pragma unroll
        for (int kb = 0; kb < 2; ++kb) {
            #pragma unroll
            for (int cb = 0; cb < 16; ++cb) {
                bf16x8 Vf = *(const bf16x8*)(vb + (cb * 2 + kb) * 512 + lane * 8);
                #pragma unroll
                for (int m = 0; m < 2; ++m)
                    O[m][cb] = __builtin_amdgcn_mfma_f32_16x16x32_bf16(
                        Pf[m][kb], Vf, O[m][cb], 0, 0, 0);
            }
        }
        __builtin_amdgcn_s_setprio(0);
        buf ^= 1;
    }
#undef STAGE

    // ---- l: full row sum = reduce lane-local partials across the 4 quads
    #pragma unroll
    for (int m = 0; m < 2; ++m) {
        lsum[m] += __shfl_xor(lsum[m], 16, 64);
        lsum[m] += __shfl_xor(lsum[m], 32, 64);
    }
    // O rows are i = m*16 + quad*4 + r; fetch that row's sum (held at lane n16 = quad*4+r)
    float inv_l[2][4];
    #pragma unroll
    for (int m = 0; m < 2; ++m)
        #pragma unroll
        for (int r = 0; r < 4; ++r)
            inv_l[m][r] = 1.f / __shfl(lsum[m], quad * 4 + r, 64);

    // ---- store normalized partials + (m=0, l)
    u16* pbase = part + ((size_t)(p * 4 + b) * N_POS + i0) * C_DIM;
    #pragma unroll
    for (int m = 0; m < 2; ++m)
        #pragma unroll
        for (int cb = 0; cb < 16; ++cb)
            #pragma unroll
            for (int r = 0; r < 4; ++r)
                pbase[(size_t)(m * 16 + quad * 4 + r) * C_DIM + cb * 16 + n16] =
                    f32_to_bf16_rn(O[m][cb][r] * inv_l[m][r]);
    if (quad == 0) {
        #pragma unroll
        for (int m = 0; m < 2; ++m)
            ml[(size_t)(p * 4 + b) * N_POS + i0 + m * 16 + n16] =
                make_float2(0.f, lsum[m]);
    }
}

// ---------------------------------------------------------------------------
// Reduce (R16 vectorized): bf16x8 part loads (16 B/lane — G13), transpose
// via LDS, + residual. ~95% of its 10.4 us BW floor.
// ---------------------------------------------------------------------------
__global__ __launch_bounds__(256) void reduce_kernel(
    const u16* __restrict__ part, const float2* __restrict__ ml,
    const float* __restrict__ x, float* __restrict__ out)
{
    const int TJ = 32;
    __shared__ float wgt[NPART][TJ];
    __shared__ float trans[C_DIM][TJ + 1];

    const int t   = threadIdx.x;
    const int blk = blockIdx.x;      // 0..511
    const int b   = blk >> 7;
    const int n0  = (blk & 127) * TJ;

    if (t < TJ) {
        int i = n0 + t;
        float s = 0.f, w[NPART];
        #pragma unroll
        for (int p = 0; p < NPART; ++p) {
            float2 a = ml[(size_t)(p * 4 + b) * N_POS + i];
            w[p] = a.y;          // m == 0 for all partitions
            s += w[p];
        }
        float inv = 1.f / s;
        #pragma unroll
        for (int p = 0; p < NPART; ++p) wgt[p][t] = w[p] * inv;
    }
    __syncthreads();

    {
        const int cp = t & 31;     // 8 channels: cp*8 .. cp*8+7
        const int ih = t >> 5;     // 8 rows in flight
        for (int ib = 0; ib < TJ; ib += 8) {
            const int i = ib + ih;
            float acc[8] = {0.f, 0.f, 0.f, 0.f, 0.f, 0.f, 0.f, 0.f};
            #pragma unroll
            for (int p = 0; p < NPART; ++p) {
                const u16* row = part + ((size_t)(p * 4 + b) * N_POS + n0 + i) * C_DIM;
                bf16x8 pv = *(const bf16x8*)(row + cp * 8);
                const float wp = wgt[p][i];
                #pragma unroll
                for (int e = 0; e < 8; ++e)
                    acc[e] += wp * bf16_to_f32((u16)pv[e]);
            }
            #pragma unroll
            for (int e = 0; e < 8; ++e)
                trans[cp * 8 + e][i] = acc[e];
        }
    }
    __syncthreads();

    {
        const int il = t & 31;
        const int cr = t >> 5;
        const float* xb = x + (size_t)b * C_DIM * N_POS;
        float* ob       = out + (size_t)b * C_DIM * N_POS;
        for (int cc = 0; cc < 32; ++cc) {
            int c = cc * 8 + cr;
            size_t g = (size_t)c * N_POS + n0 + il;
            ob[g] = trans[c][il] + xb[g];
        }
    }
}

extern "C" void kernel_launch(void* const* d_in, const int* in_sizes, int n_in,
                              void* d_out, int out_size, void* d_ws, size_t ws_size,
                              hipStream_t stream) {
    const float* x  = (const float*)d_in[0];
    const float* Wq = (const float*)d_in[1];
    const float* bq = (const float*)d_in[2];
    const float* Wk = (const float*)d_in[3];
    const float* bk = (const float*)d_in[4];
    const float* Wv = (const float*)d_in[5];
    const float* bv = (const float*)d_in[6];
    float* out = (float*)d_out;

    // ws layout (44.5 MiB == R1-proven bound):
    //   0 MiB  qhi (1)   1 MiB  qlo (1)
    //   2 MiB  kth [B,64,4,512] u16 (1)   3 MiB  ktl (1)
    //   4 MiB  vtile [B,64,32,512] u16 (8)
    //  12 MiB  part [4,B,N,C] bf16 (32)
    //  44 MiB  ml [4,B,N] float2 (0.5)
    char* ws = (char*)d_ws;
    u16*    qhi   = (u16*)(ws);
    u16*    qlo   = (u16*)(ws + (1ull << 20));
    u16*    kth   = (u16*)(ws + (2ull << 20));
    u16*    ktl   = (u16*)(ws + (3ull << 20));
    u16*    vtile = (u16*)(ws + (4ull << 20));
    u16*    part  = (u16*)(ws + (12ull << 20));
    float2* mlp   = (float2*)(ws + (44ull << 20));

    hipLaunchKernelGGL(proj_kernel, dim3(256), dim3(256), 0, stream,
                       x, Wq, bq, Wk, bk, Wv, bv, qhi, qlo, kth, ktl, vtile);
    hipLaunchKernelGGL(flash_kernel, dim3(256), dim3(512), 0, stream,
                       qhi, qlo, kth, ktl, vtile, part, mlp);
    hipLaunchKernelGGL(reduce_kernel, dim3(512), dim3(256), 0, stream,
                       part, mlp, x, out);
}